// Round 1
// baseline (1422.816 us; speedup 1.0000x reference)
//
#include <hip/hip_runtime.h>
#include <hip/hip_bf16.h>
#include <math.h>

#define NB 2048
#define NC 8
#define NS 32
#define ND 32
#define NH 512
#define NROWS (NB*NS)
#define NNEG 512

// ws layout (float offsets)
#define WS_SSUM   0         // [8][32]        256
#define WS_SPROD  256       // [8][32][32]    8192
#define WS_W1T    8448      // [8][32][512]   131072  (W1eff transposed: [c][d][h])
#define WS_B1EFF  139520    // [8][512]       4096
#define WS_Z      143616    // [2048][8][32]  524288
#define WS_ZN     667904    // [2048][8][32]  524288
#define WS_POS    1192192   // [2048]         2048
// total 1194240 floats ≈ 4.78 MB

// ---------------- K1: per-channel first/second moments of x ----------------
__global__ void k_stats(const float* __restrict__ x,
                        float* __restrict__ Ssum, float* __restrict__ Sprod) {
  int c = blockIdx.y;
  int b0 = blockIdx.x * 32;
  int t = threadIdx.x;
  __shared__ float xs[32][32];
  int i = t >> 3;        // 0..31
  int jg = t & 7;        // 0..7 -> j group of 4
  float macc[4] = {0.f,0.f,0.f,0.f};
  float sacc = 0.f;
  for (int bb = 0; bb < 32; ++bb) {
    int b = b0 + bb;
    const float4* src = (const float4*)(x + ((size_t)(b*NC + c))*1024);
    ((float4*)(&xs[0][0]))[t] = src[t];
    __syncthreads();
    #pragma unroll 4
    for (int s = 0; s < 32; ++s) {
      float xi = xs[s][i];
      #pragma unroll
      for (int jj = 0; jj < 4; ++jj)
        macc[jj] = fmaf(xi, xs[s][jg*4+jj], macc[jj]);
    }
    if (t < 32) {
      #pragma unroll 4
      for (int s = 0; s < 32; ++s) sacc += xs[s][t];
    }
    __syncthreads();
  }
  #pragma unroll
  for (int jj = 0; jj < 4; ++jj)
    atomicAdd(&Sprod[(c*32 + i)*32 + jg*4 + jj], macc[jj]);
  if (t < 32) atomicAdd(&Ssum[c*32 + t], sacc);
}

// ---------------- K2: fold BN stats into W1 (transposed) ----------------
__global__ void k_fold(const float* __restrict__ W1, const float* __restrict__ b1,
                       const float* __restrict__ gamma, const float* __restrict__ beta,
                       const float* __restrict__ Ssum, const float* __restrict__ Sprod,
                       float* __restrict__ W1T, float* __restrict__ b1eff) {
  int g = blockIdx.x*256 + threadIdx.x;   // 0..4095
  int c = g >> 9, h = g & 511;
  const float invN = 1.0f / (float)NROWS;
  float w[32];
  #pragma unroll
  for (int d = 0; d < 32; ++d) w[d] = W1[h*32 + d];
  const float* M = Sprod + c*1024;
  float q = 0.f;
  for (int j = 0; j < 32; ++j) {
    float v = 0.f;
    #pragma unroll
    for (int i = 0; i < 32; ++i) v = fmaf(w[i], M[i*32 + j], v);
    q = fmaf(v, w[j], q);
  }
  float wmu = 0.f;
  #pragma unroll
  for (int d = 0; d < 32; ++d) wmu = fmaf(w[d], Ssum[c*32 + d]*invN, wmu);
  float bb = b1[h];
  float mean = wmu + bb;
  float e2 = q*invN + 2.f*bb*wmu + bb*bb;
  float var = e2 - mean*mean;
  float alpha = gamma[h] * rsqrtf(var + 1e-5f);
  #pragma unroll
  for (int d = 0; d < 32; ++d) W1T[((size_t)c*32 + d)*512 + h] = w[d]*alpha;
  b1eff[c*512 + h] = (bb - mean)*alpha + beta[h];
}

// ---------------- K3: fused  hn -> relu -> y -> Z  per (c,b) block ----------------
__global__ __launch_bounds__(256) void k_main(
    const float* __restrict__ x, const float* __restrict__ W1T,
    const float* __restrict__ b1eff, const float* __restrict__ W2,
    const float* __restrict__ b2, const float* __restrict__ fcW,
    const float* __restrict__ fcb, float* __restrict__ Z) {
  int blk = blockIdx.x;
  int c = blk >> 11;          // / 2048
  int b = blk & 2047;
  int t = threadIdx.x;
  __shared__ float xs[32][32];      // x tile [s][d]
  __shared__ float rbuf[32][256];   // relu(hn) chunk [s][h2]
  __shared__ float ybuf[32][32];    // y [s][d]
  __shared__ float red[8][32];

  const float4* src = (const float4*)(x + ((size_t)(b*NC + c))*1024);
  ((float4*)(&xs[0][0]))[t] = src[t];
  #pragma unroll
  for (int p = 0; p < 4; ++p) { int i = t + p*256; ybuf[i>>5][i&31] = b2[i&31]; }
  __syncthreads();

  const float* W1c = W1T + (size_t)c*32*512;
  int s0 = t >> 5;            // 0..7
  int d0 = t & 31;

  for (int hc = 0; hc < 512; hc += 256) {
    int h = hc + t;
    float acc[32];
    float binit = b1eff[c*512 + h];
    #pragma unroll
    for (int s = 0; s < 32; ++s) acc[s] = binit;
    #pragma unroll 2
    for (int dq = 0; dq < 8; ++dq) {
      float w0 = W1c[(4*dq+0)*512 + h];
      float w1 = W1c[(4*dq+1)*512 + h];
      float w2v = W1c[(4*dq+2)*512 + h];
      float w3 = W1c[(4*dq+3)*512 + h];
      #pragma unroll
      for (int s = 0; s < 32; ++s) {
        float4 xv = ((const float4*)&xs[s][0])[dq];
        acc[s] = fmaf(xv.x, w0, acc[s]);
        acc[s] = fmaf(xv.y, w1, acc[s]);
        acc[s] = fmaf(xv.z, w2v, acc[s]);
        acc[s] = fmaf(xv.w, w3, acc[s]);
      }
    }
    #pragma unroll
    for (int s = 0; s < 32; ++s) rbuf[s][t] = fmaxf(acc[s], 0.f);
    __syncthreads();

    // y[s][d] += sum_{h2} r[s][h2] * W2[d][hc+h2]
    const float4* w2row = (const float4*)(W2 + (size_t)d0*512 + hc);
    float a[4] = {0.f,0.f,0.f,0.f};
    #pragma unroll 4
    for (int hq = 0; hq < 64; ++hq) {
      float4 wq = w2row[hq];
      #pragma unroll
      for (int p = 0; p < 4; ++p) {
        float4 rv = ((const float4*)&rbuf[s0 + 8*p][0])[hq];
        a[p] += rv.x*wq.x + rv.y*wq.y + rv.z*wq.z + rv.w*wq.w;
      }
    }
    #pragma unroll
    for (int p = 0; p < 4; ++p) ybuf[s0 + 8*p][d0] += a[p];
    __syncthreads();
  }

  // Z[b][c][o] = sum_f yflat[f] * fcW[o][f] + fcb[o]
  int o = d0, g = s0;
  const float4* yf4 = ((const float4*)(&ybuf[0][0])) + g*32;
  const float4* fc4 = (const float4*)(fcW + (size_t)o*1024 + g*128);
  float part = 0.f;
  #pragma unroll 8
  for (int k = 0; k < 32; ++k) {
    float4 yv = yf4[k]; float4 fv = fc4[k];
    part += yv.x*fv.x + yv.y*fv.y + yv.z*fv.z + yv.w*fv.w;
  }
  red[g][o] = part;
  __syncthreads();
  if (t < 32) {
    float z = fcb[t];
    #pragma unroll
    for (int gg = 0; gg < 8; ++gg) z += red[gg][t];
    Z[((size_t)b*NC + c)*32 + t] = z;
  }
}

// ---------------- K4: normalize, pos_sim, Z_out ----------------
__global__ void k_znorm(const float* __restrict__ Z, float* __restrict__ Zn,
                        float* __restrict__ possim, float* __restrict__ out) {
  int b = blockIdx.x;
  int t = threadIdx.x;        // 256: t = c*32 + d
  float v = Z[(size_t)b*256 + t];
  float n2 = v*v;
  #pragma unroll
  for (int m = 16; m >= 1; m >>= 1) n2 += __shfl_xor(n2, m, 64);
  float nrm = fmaxf(sqrtf(n2), 1e-8f);
  float zn = v / nrm;
  Zn[(size_t)b*256 + t] = zn;
  __shared__ float sz[256];
  __shared__ float szn[256];
  sz[t] = v; szn[t] = zn;
  __syncthreads();
  if (t < 32) {
    float s = 0.f;
    #pragma unroll
    for (int cc = 0; cc < 8; ++cc) s += sz[cc*32 + t];
    out[(size_t)b*32 + t] = s * 0.125f;
    // pos_sim via sum identity: sum_{j<k} G_jk = (sum_d S_d^2 - sum zn^2)/2
    float sd = 0.f, t1 = 0.f;
    #pragma unroll
    for (int cc = 0; cc < 8; ++cc) {
      float z2 = szn[cc*32 + t];
      sd += z2; t1 = fmaf(z2, z2, t1);
    }
    float t2 = sd*sd;
    #pragma unroll
    for (int m = 16; m >= 1; m >>= 1) {
      t2 += __shfl_xor(t2, m, 64);
      t1 += __shfl_xor(t1, m, 64);
    }
    if (t == 0) possim[b] = (t2 - t1)*0.5f/28.0f;
  }
}

// ---------------- K5: negative-sim gather + final l ----------------
__global__ void k_negsim(const float* __restrict__ Zn, const int* __restrict__ neg_idx,
                         const float* __restrict__ possim, float* __restrict__ lout) {
  int b = blockIdx.x;
  int t = threadIdx.x;   // 256
  __shared__ float4 zb[64];
  if (t < 64) zb[t] = ((const float4*)(Zn + (size_t)b*256))[t];
  __syncthreads();
  float esum = 0.f;
  #pragma unroll
  for (int p = 0; p < 2; ++p) {
    int n = t + p*256;
    int raw = neg_idx[(size_t)b*NNEG + n];
    int j = raw + (raw >= b ? 1 : 0);
    const float4* zr = (const float4*)(Zn + (size_t)j*256);
    float dot = 0.f;
    #pragma unroll 8
    for (int k = 0; k < 64; ++k) {
      float4 r = zr[k]; float4 zv = zb[k];
      dot += zv.x*r.x + zv.y*r.y + zv.z*r.z + zv.w*r.w;
    }
    esum += expf(dot * 0.25f);   // (dot/8)/TEMP = dot * 0.25
  }
  #pragma unroll
  for (int m = 32; m >= 1; m >>= 1) esum += __shfl_xor(esum, m, 64);
  __shared__ float rs[4];
  int wid = t >> 6, lane = t & 63;
  if (lane == 0) rs[wid] = esum;
  __syncthreads();
  if (t == 0) {
    float tot = rs[0] + rs[1] + rs[2] + rs[3];
    lout[b] = expf(possim[b]*2.0f) / tot;
  }
}

extern "C" void kernel_launch(void* const* d_in, const int* in_sizes, int n_in,
                              void* d_out, int out_size, void* d_ws, size_t ws_size,
                              hipStream_t stream) {
  const float* x     = (const float*)d_in[0];
  const float* W1    = (const float*)d_in[1];
  const float* b1    = (const float*)d_in[2];
  const float* gamma = (const float*)d_in[3];
  const float* beta  = (const float*)d_in[4];
  const float* W2    = (const float*)d_in[5];
  const float* b2    = (const float*)d_in[6];
  const float* fcW   = (const float*)d_in[7];
  const float* fcb   = (const float*)d_in[8];
  const int*   nidx  = (const int*)d_in[9];
  float* ws = (float*)d_ws;
  float* Ssum   = ws + WS_SSUM;
  float* Sprod  = ws + WS_SPROD;
  float* W1T    = ws + WS_W1T;
  float* b1eff  = ws + WS_B1EFF;
  float* Z      = ws + WS_Z;
  float* Zn     = ws + WS_ZN;
  float* possim = ws + WS_POS;
  float* out = (float*)d_out;

  hipMemsetAsync(ws, 0, (256 + 8192)*sizeof(float), stream);
  k_stats<<<dim3(64, 8), 256, 0, stream>>>(x, Ssum, Sprod);
  k_fold<<<16, 256, 0, stream>>>(W1, b1, gamma, beta, Ssum, Sprod, W1T, b1eff);
  k_main<<<NC*NB, 256, 0, stream>>>(x, W1T, b1eff, W2, b2, fcW, fcb, Z);
  k_znorm<<<NB, 256, 0, stream>>>(Z, Zn, possim, out);
  k_negsim<<<NB, 256, 0, stream>>>(Zn, nidx, possim, out + NB*32);
}

// Round 2
// 366.179 us; speedup vs baseline: 3.8856x; 3.8856x over previous
//
#include <hip/hip_runtime.h>
#include <hip/hip_bf16.h>
#include <math.h>

#define NB 2048
#define NC 8
#define NNEG 512

typedef __attribute__((ext_vector_type(8))) short bf16x8;
typedef __attribute__((ext_vector_type(4))) float f32x4;

static __device__ __forceinline__ unsigned short f2b(float f) {
  __hip_bfloat16 h = __float2bfloat16(f);
  return *reinterpret_cast<unsigned short*>(&h);
}

// ---- ws layout (float offsets) ----
#define WS_SSUM   0          // [8][32]
#define WS_SPROD  256        // [8][32][32]
#define WS_B1EFF  8448       // [8][512] f32
#define WS_Z      12544      // [2048][8][32] f32
#define WS_ZN     536832     // [2048][8][32] f32
#define WS_POS    1061120    // [2048] f32
#define WS_W1B    1063168    // ushort [8][512][32]  (bf16, N x K row-major)
#define WS_W2B    1128704    // ushort [32][512]
#define WS_FCWB   1136896    // ushort [32][1024]
// end: 1153280 floats = 4.61 MB (< round-1 usage, ws_size-safe)

// ---------------- K1: per-channel first/second moments of x ----------------
__global__ __launch_bounds__(256) void k_stats(const float* __restrict__ x,
                        float* __restrict__ Ssum, float* __restrict__ Sprod) {
  int c = blockIdx.y;
  int t = threadIdx.x;
  __shared__ float xs[32][32];
  int i = t >> 3, jg = t & 7;
  float macc[4] = {0.f, 0.f, 0.f, 0.f};
  float sacc = 0.f;
  float4 nxt = ((const float4*)(x + ((size_t)(blockIdx.x * NC + c)) * 1024))[t];
  for (int it = 0; it < 8; ++it) {
    __syncthreads();
    ((float4*)(&xs[0][0]))[t] = nxt;
    __syncthreads();
    if (it < 7) {
      int b = blockIdx.x + 256 * (it + 1);
      nxt = ((const float4*)(x + ((size_t)(b * NC + c)) * 1024))[t];
    }
    #pragma unroll 4
    for (int s = 0; s < 32; ++s) {
      float xi = xs[s][i];
      #pragma unroll
      for (int jj = 0; jj < 4; ++jj)
        macc[jj] = fmaf(xi, xs[s][jg * 4 + jj], macc[jj]);
    }
    if (t < 32) {
      #pragma unroll 4
      for (int s = 0; s < 32; ++s) sacc += xs[s][t];
    }
  }
  #pragma unroll
  for (int jj = 0; jj < 4; ++jj)
    atomicAdd(&Sprod[(c * 32 + i) * 32 + jg * 4 + jj], macc[jj]);
  if (t < 32) atomicAdd(&Ssum[c * 32 + t], sacc);
}

// ---------------- K2: fold BN into W1 -> bf16 [c][h][d], b1eff f32 ----------------
__global__ void k_fold(const float* __restrict__ W1, const float* __restrict__ b1,
                       const float* __restrict__ gamma, const float* __restrict__ beta,
                       const float* __restrict__ Ssum, const float* __restrict__ Sprod,
                       unsigned short* __restrict__ W1B, float* __restrict__ b1eff) {
  int g = blockIdx.x * 256 + threadIdx.x;   // 0..4095
  int c = g >> 9, h = g & 511;
  const float invN = 1.0f / (float)(NB * 32);
  float w[32];
  #pragma unroll
  for (int d = 0; d < 32; ++d) w[d] = W1[h * 32 + d];
  const float* M = Sprod + c * 1024;
  float q = 0.f;
  for (int j = 0; j < 32; ++j) {
    float v = 0.f;
    #pragma unroll
    for (int i = 0; i < 32; ++i) v = fmaf(w[i], M[i * 32 + j], v);
    q = fmaf(v, w[j], q);
  }
  float wmu = 0.f;
  #pragma unroll
  for (int d = 0; d < 32; ++d) wmu = fmaf(w[d], Ssum[c * 32 + d] * invN, wmu);
  float bb = b1[h];
  float mean = wmu + bb;
  float e2 = q * invN + 2.f * bb * wmu + bb * bb;
  float var = e2 - mean * mean;
  float alpha = gamma[h] * rsqrtf(var + 1e-5f);
  #pragma unroll
  for (int d = 0; d < 32; ++d)
    W1B[((size_t)c * 512 + h) * 32 + d] = f2b(w[d] * alpha);
  b1eff[c * 512 + h] = (bb - mean) * alpha + beta[h];
}

// ---------------- K2b: convert W2, fcW to bf16 ----------------
__global__ void k_cvt(const float* __restrict__ W2, const float* __restrict__ fcW,
                      unsigned short* __restrict__ W2B, unsigned short* __restrict__ fcWB) {
  int i = blockIdx.x * 256 + threadIdx.x;   // 0..32767
  if (i < 32 * 512) W2B[i] = f2b(W2[i]);
  fcWB[i] = f2b(fcW[i]);
}

// ---------------- K3: fused MFMA  x->h->relu->y->Z  (128 rows/block) ----------------
__global__ __launch_bounds__(256) void k_main(
    const float* __restrict__ x, const unsigned short* __restrict__ W1B,
    const float* __restrict__ b1eff, const unsigned short* __restrict__ W2B,
    const float* __restrict__ b2, const unsigned short* __restrict__ fcWB,
    const float* __restrict__ fcb, float* __restrict__ Z) {
  int c = blockIdx.y;
  int bt = blockIdx.x;            // 512 tiles of 4 b each
  int t = threadIdx.x;
  int w = t >> 6, l = t & 63;
  int lr = l & 15, lg = l >> 4;

  __shared__ unsigned short xs[128][40];    // x tile bf16, padded
  __shared__ unsigned short rbuf[128][72];  // relu(hn) chunk (64 h), padded
  __shared__ unsigned short ybf[4][1024];   // y bf16 per b, flat [s*32+d]
  __shared__ float zred[2][4][32];

  // ---- stage x (f32 -> bf16); each wave writes/reads only its own 32 rows ----
  {
    int r = t >> 1;
    int col0 = (t & 1) * 16;
    int b = bt * 4 + (r >> 5);
    const float* src = x + (((size_t)b * NC + c) * 32 + (r & 31)) * 32 + col0;
    float4 v0 = ((const float4*)src)[0];
    float4 v1 = ((const float4*)src)[1];
    float4 v2 = ((const float4*)src)[2];
    float4 v3 = ((const float4*)src)[3];
    bf16x8 p0, p1;
    p0[0] = (short)f2b(v0.x); p0[1] = (short)f2b(v0.y);
    p0[2] = (short)f2b(v0.z); p0[3] = (short)f2b(v0.w);
    p0[4] = (short)f2b(v1.x); p0[5] = (short)f2b(v1.y);
    p0[6] = (short)f2b(v1.z); p0[7] = (short)f2b(v1.w);
    p1[0] = (short)f2b(v2.x); p1[1] = (short)f2b(v2.y);
    p1[2] = (short)f2b(v2.z); p1[3] = (short)f2b(v2.w);
    p1[4] = (short)f2b(v3.x); p1[5] = (short)f2b(v3.y);
    p1[6] = (short)f2b(v3.z); p1[7] = (short)f2b(v3.w);
    *(bf16x8*)&xs[r][col0] = p0;
    *(bf16x8*)&xs[r][col0 + 8] = p1;
  }

  const unsigned short* W1c = W1B + (size_t)c * 512 * 32;
  const float* b1e = b1eff + c * 512;
  int row0 = w * 32;
  const f32x4 fzero = {0.f, 0.f, 0.f, 0.f};

  // A-fragments of x (K=32 complete): rows lr / 16+lr of this wave's block
  bf16x8 af0 = *(const bf16x8*)&xs[row0 + lr][lg * 8];
  bf16x8 af1 = *(const bf16x8*)&xs[row0 + 16 + lr][lg * 8];

  float bd0 = b2[lr], bd1 = b2[16 + lr];
  f32x4 yacc00 = {bd0, bd0, bd0, bd0};
  f32x4 yacc01 = {bd1, bd1, bd1, bd1};
  f32x4 yacc10 = yacc00;
  f32x4 yacc11 = yacc01;

  for (int ch = 0; ch < 8; ++ch) {
    int hc = ch * 64;
    // GEMM1: hn = relu(x @ W1eff^T + b1eff) for 64 h, into rbuf
    #pragma unroll
    for (int nt = 0; nt < 4; ++nt) {
      int h = hc + nt * 16 + lr;
      bf16x8 bf = *(const bf16x8*)&W1c[(size_t)h * 32 + lg * 8];
      float bias = b1e[h];
      f32x4 d0 = __builtin_amdgcn_mfma_f32_16x16x32_bf16(af0, bf, fzero, 0, 0, 0);
      f32x4 d1 = __builtin_amdgcn_mfma_f32_16x16x32_bf16(af1, bf, fzero, 0, 0, 0);
      #pragma unroll
      for (int r = 0; r < 4; ++r) {
        rbuf[row0 + lg * 4 + r][nt * 16 + lr]      = f2b(fmaxf(d0[r] + bias, 0.f));
        rbuf[row0 + 16 + lg * 4 + r][nt * 16 + lr] = f2b(fmaxf(d1[r] + bias, 0.f));
      }
    }
    // GEMM2: y += hn_chunk @ W2_chunk^T  (2 K-steps of 32)
    #pragma unroll
    for (int ks = 0; ks < 2; ++ks) {
      bf16x8 ha0 = *(const bf16x8*)&rbuf[row0 + lr][ks * 32 + lg * 8];
      bf16x8 ha1 = *(const bf16x8*)&rbuf[row0 + 16 + lr][ks * 32 + lg * 8];
      int kk = hc + ks * 32 + lg * 8;
      bf16x8 wb0 = *(const bf16x8*)&W2B[(size_t)lr * 512 + kk];
      bf16x8 wb1 = *(const bf16x8*)&W2B[(size_t)(16 + lr) * 512 + kk];
      yacc00 = __builtin_amdgcn_mfma_f32_16x16x32_bf16(ha0, wb0, yacc00, 0, 0, 0);
      yacc01 = __builtin_amdgcn_mfma_f32_16x16x32_bf16(ha0, wb1, yacc01, 0, 0, 0);
      yacc10 = __builtin_amdgcn_mfma_f32_16x16x32_bf16(ha1, wb0, yacc10, 0, 0, 0);
      yacc11 = __builtin_amdgcn_mfma_f32_16x16x32_bf16(ha1, wb1, yacc11, 0, 0, 0);
    }
  }

  // y (f32 frags) -> ybf bf16: wave w == b-index w; s = mt*16 + lg*4 + r
  #pragma unroll
  for (int r = 0; r < 4; ++r) {
    ybf[w][(lg * 4 + r) * 32 + lr]           = f2b(yacc00[r]);
    ybf[w][(lg * 4 + r) * 32 + 16 + lr]      = f2b(yacc01[r]);
    ybf[w][(16 + lg * 4 + r) * 32 + lr]      = f2b(yacc10[r]);
    ybf[w][(16 + lg * 4 + r) * 32 + 16 + lr] = f2b(yacc11[r]);
  }
  __syncthreads();

  // ---- fc via MFMA: M = 4 b's (of 16, rows clamped), N = 32 o, K = 1024 ----
  int nt = w & 1, kh = w >> 1;
  int arow = (lr < 4) ? lr : 3;
  f32x4 zacc = {0.f, 0.f, 0.f, 0.f};
  #pragma unroll
  for (int ks = 0; ks < 16; ++ks) {
    int k0 = (kh * 16 + ks) * 32 + lg * 8;
    bf16x8 afc = *(const bf16x8*)&ybf[arow][k0];
    bf16x8 bfc = *(const bf16x8*)&fcWB[(size_t)(nt * 16 + lr) * 1024 + k0];
    zacc = __builtin_amdgcn_mfma_f32_16x16x32_bf16(afc, bfc, zacc, 0, 0, 0);
  }
  if (lg == 0) {
    #pragma unroll
    for (int r = 0; r < 4; ++r) zred[kh][r][nt * 16 + lr] = zacc[r];
  }
  __syncthreads();
  if (t < 128) {
    int bloc = t >> 5, o = t & 31;
    Z[((size_t)(bt * 4 + bloc) * NC + c) * 32 + o] =
        zred[0][bloc][o] + zred[1][bloc][o] + fcb[o];
  }
}

// ---------------- K4: normalize, pos_sim, Z_out ----------------
__global__ void k_znorm(const float* __restrict__ Z, float* __restrict__ Zn,
                        float* __restrict__ possim, float* __restrict__ out) {
  int b = blockIdx.x;
  int t = threadIdx.x;        // 256: t = c*32 + d
  float v = Z[(size_t)b * 256 + t];
  float n2 = v * v;
  #pragma unroll
  for (int m = 16; m >= 1; m >>= 1) n2 += __shfl_xor(n2, m, 64);
  float nrm = fmaxf(sqrtf(n2), 1e-8f);
  float zn = v / nrm;
  Zn[(size_t)b * 256 + t] = zn;
  __shared__ float sz[256];
  __shared__ float szn[256];
  sz[t] = v; szn[t] = zn;
  __syncthreads();
  if (t < 32) {
    float s = 0.f;
    #pragma unroll
    for (int cc = 0; cc < 8; ++cc) s += sz[cc * 32 + t];
    out[(size_t)b * 32 + t] = s * 0.125f;
    float sd = 0.f, t1 = 0.f;
    #pragma unroll
    for (int cc = 0; cc < 8; ++cc) {
      float z2 = szn[cc * 32 + t];
      sd += z2; t1 = fmaf(z2, z2, t1);
    }
    float t2 = sd * sd;
    #pragma unroll
    for (int m = 16; m >= 1; m >>= 1) {
      t2 += __shfl_xor(t2, m, 64);
      t1 += __shfl_xor(t1, m, 64);
    }
    if (t == 0) possim[b] = (t2 - t1) * 0.5f / 28.0f;
  }
}

// ---------------- K5: negative-sim gather + final l ----------------
__global__ void k_negsim(const float* __restrict__ Zn, const int* __restrict__ neg_idx,
                         const float* __restrict__ possim, float* __restrict__ lout) {
  int b = blockIdx.x;
  int t = threadIdx.x;   // 256
  __shared__ float4 zb[64];
  if (t < 64) zb[t] = ((const float4*)(Zn + (size_t)b * 256))[t];
  __syncthreads();
  float esum = 0.f;
  #pragma unroll
  for (int p = 0; p < 2; ++p) {
    int n = t + p * 256;
    int raw = neg_idx[(size_t)b * NNEG + n];
    int j = raw + (raw >= b ? 1 : 0);
    const float4* zr = (const float4*)(Zn + (size_t)j * 256);
    float dot = 0.f;
    #pragma unroll 8
    for (int k = 0; k < 64; ++k) {
      float4 r = zr[k]; float4 zv = zb[k];
      dot += zv.x * r.x + zv.y * r.y + zv.z * r.z + zv.w * r.w;
    }
    esum += expf(dot * 0.25f);
  }
  #pragma unroll
  for (int m = 32; m >= 1; m >>= 1) esum += __shfl_xor(esum, m, 64);
  __shared__ float rs[4];
  int wid = t >> 6, lane = t & 63;
  if (lane == 0) rs[wid] = esum;
  __syncthreads();
  if (t == 0) {
    float tot = rs[0] + rs[1] + rs[2] + rs[3];
    lout[b] = expf(possim[b] * 2.0f) / tot;
  }
}

extern "C" void kernel_launch(void* const* d_in, const int* in_sizes, int n_in,
                              void* d_out, int out_size, void* d_ws, size_t ws_size,
                              hipStream_t stream) {
  const float* x     = (const float*)d_in[0];
  const float* W1    = (const float*)d_in[1];
  const float* b1    = (const float*)d_in[2];
  const float* gamma = (const float*)d_in[3];
  const float* beta  = (const float*)d_in[4];
  const float* W2    = (const float*)d_in[5];
  const float* b2    = (const float*)d_in[6];
  const float* fcW   = (const float*)d_in[7];
  const float* fcb   = (const float*)d_in[8];
  const int*   nidx  = (const int*)d_in[9];
  float* ws = (float*)d_ws;
  float* Ssum   = ws + WS_SSUM;
  float* Sprod  = ws + WS_SPROD;
  float* b1eff  = ws + WS_B1EFF;
  float* Z      = ws + WS_Z;
  float* Zn     = ws + WS_ZN;
  float* possim = ws + WS_POS;
  unsigned short* W1Bp  = (unsigned short*)(ws + WS_W1B);
  unsigned short* W2Bp  = (unsigned short*)(ws + WS_W2B);
  unsigned short* fcWBp = (unsigned short*)(ws + WS_FCWB);
  float* out = (float*)d_out;

  hipMemsetAsync(ws, 0, (256 + 8192) * sizeof(float), stream);
  k_stats<<<dim3(256, 8), 256, 0, stream>>>(x, Ssum, Sprod);
  k_fold<<<16, 256, 0, stream>>>(W1, b1, gamma, beta, Ssum, Sprod, W1Bp, b1eff);
  k_cvt<<<128, 256, 0, stream>>>(W2, fcW, W2Bp, fcWBp);
  k_main<<<dim3(512, 8), 256, 0, stream>>>(x, W1Bp, b1eff, W2Bp, b2, fcWBp, fcb, Z);
  k_znorm<<<NB, 256, 0, stream>>>(Z, Zn, possim, out);
  k_negsim<<<NB, 256, 0, stream>>>(Zn, nidx, possim, out + NB * 32);
}

// Round 3
// 257.005 us; speedup vs baseline: 5.5361x; 1.4248x over previous
//
#include <hip/hip_runtime.h>
#include <hip/hip_bf16.h>
#include <math.h>

#define NB 2048
#define NC 8
#define NNEG 512

typedef __attribute__((ext_vector_type(8))) short bf16x8;
typedef __attribute__((ext_vector_type(4))) float f32x4;

static __device__ __forceinline__ unsigned short f2b(float f) {
  __hip_bfloat16 h = __float2bfloat16(f);
  return *reinterpret_cast<unsigned short*>(&h);
}
static __device__ __forceinline__ unsigned int packbf2(float a, float b) {
  return (unsigned int)f2b(a) | ((unsigned int)f2b(b) << 16);
}

// ---- ws layout (float offsets) ----
#define WS_SSUM   0          // [8][32]
#define WS_SPROD  256        // [8][32][32]
#define WS_B1EFF  8448       // [8][512] f32
#define WS_Z      12544      // [2048][8][32] f32
#define WS_POS    536832     // [2048] f32
#define WS_W1B    538880     // ushort [8][512][32]
#define WS_W2B    604416     // ushort [32][512]
#define WS_FCWB   612608     // ushort [32][1024]
#define WS_ZNB    628992     // ushort [2048][256] (bf16 Zn)
// end: 891136 floats = 3.56 MB

// ---------------- K1: per-channel first/second moments of x ----------------
__global__ __launch_bounds__(256) void k_stats(const float* __restrict__ x,
                        float* __restrict__ Ssum, float* __restrict__ Sprod) {
  int c = blockIdx.y;
  int t = threadIdx.x;
  __shared__ float xs[32][32];
  int i = t >> 3, jg = t & 7;
  float macc[4] = {0.f, 0.f, 0.f, 0.f};
  float sacc = 0.f;
  float4 nxt = ((const float4*)(x + ((size_t)(blockIdx.x * NC + c)) * 1024))[t];
  for (int it = 0; it < 8; ++it) {
    __syncthreads();
    ((float4*)(&xs[0][0]))[t] = nxt;
    __syncthreads();
    if (it < 7) {
      int b = blockIdx.x + 256 * (it + 1);
      nxt = ((const float4*)(x + ((size_t)(b * NC + c)) * 1024))[t];
    }
    #pragma unroll 4
    for (int s = 0; s < 32; ++s) {
      float xi = xs[s][i];
      #pragma unroll
      for (int jj = 0; jj < 4; ++jj)
        macc[jj] = fmaf(xi, xs[s][jg * 4 + jj], macc[jj]);
    }
    if (t < 32) {
      #pragma unroll 4
      for (int s = 0; s < 32; ++s) sacc += xs[s][t];
    }
  }
  #pragma unroll
  for (int jj = 0; jj < 4; ++jj)
    atomicAdd(&Sprod[(c * 32 + i) * 32 + jg * 4 + jj], macc[jj]);
  if (t < 32) atomicAdd(&Ssum[c * 32 + t], sacc);
}

// ---------------- K2: fold BN into W1 (bf16) + convert W2/fcW ----------------
__global__ void k_foldcvt(const float* __restrict__ W1, const float* __restrict__ b1,
                       const float* __restrict__ gamma, const float* __restrict__ beta,
                       const float* __restrict__ Ssum, const float* __restrict__ Sprod,
                       const float* __restrict__ W2, const float* __restrict__ fcW,
                       unsigned short* __restrict__ W1B, float* __restrict__ b1eff,
                       unsigned short* __restrict__ W2B, unsigned short* __restrict__ fcWB) {
  if (blockIdx.x >= 16) {
    int i = (blockIdx.x - 16) * 256 + threadIdx.x;   // 0..32767
    if (i < 32 * 512) W2B[i] = f2b(W2[i]);
    fcWB[i] = f2b(fcW[i]);
    return;
  }
  int g = blockIdx.x * 256 + threadIdx.x;   // 0..4095
  int c = g >> 9, h = g & 511;
  const float invN = 1.0f / (float)(NB * 32);
  float w[32];
  #pragma unroll
  for (int d = 0; d < 32; ++d) w[d] = W1[h * 32 + d];
  const float* M = Sprod + c * 1024;
  float q = 0.f;
  for (int j = 0; j < 32; ++j) {
    float v = 0.f;
    #pragma unroll
    for (int i2 = 0; i2 < 32; ++i2) v = fmaf(w[i2], M[i2 * 32 + j], v);
    q = fmaf(v, w[j], q);
  }
  float wmu = 0.f;
  #pragma unroll
  for (int d = 0; d < 32; ++d) wmu = fmaf(w[d], Ssum[c * 32 + d] * invN, wmu);
  float bb = b1[h];
  float mean = wmu + bb;
  float e2 = q * invN + 2.f * bb * wmu + bb * bb;
  float var = e2 - mean * mean;
  float alpha = gamma[h] * rsqrtf(var + 1e-5f);
  #pragma unroll
  for (int d = 0; d < 32; ++d)
    W1B[((size_t)c * 512 + h) * 32 + d] = f2b(w[d] * alpha);
  b1eff[c * 512 + h] = (bb - mean) * alpha + beta[h];
}

// ---------------- K3: fused MFMA  x->h->relu->y->Z  (8 b / block) ----------------
// Swapped operands: GEMM1 = mfma(W1frag, xfrag) -> lane holds 4 consecutive h for
// fixed s -> packed ds_write_b64. GEMM2 = mfma(W2frag, hfrag) -> 4 consecutive d.
__global__ __launch_bounds__(256, 4) void k_main(
    const float* __restrict__ x, const unsigned short* __restrict__ W1B,
    const float* __restrict__ b1eff, const unsigned short* __restrict__ W2B,
    const float* __restrict__ b2, const unsigned short* __restrict__ fcWB,
    const float* __restrict__ fcb, float* __restrict__ Z) {
  int c = blockIdx.y;
  int bt = blockIdx.x;            // 256 tiles of 8 b each
  int t = threadIdx.x;
  int w = t >> 6, l = t & 63;
  int lr = l & 15, lg = l >> 4;

  // wave-private union: rbuf rows [64w,64w+64) x 40  ==  ybf b {2w,2w+1} x 1280
  __shared__ unsigned short buf[8 * 1280];   // 20480 B
  __shared__ float zred[2][8][32];

  const unsigned short* W1c = W1B + (size_t)c * 512 * 32;
  const float* b1e = b1eff + c * 512;

  // ---- x B-fragments direct from global (4 sub-blocks of 16 rows each) ----
  bf16x8 xf[4];
  #pragma unroll
  for (int sb = 0; sb < 4; ++sb) {
    int bl = 2 * w + (sb >> 1);
    int s = (sb & 1) * 16 + lr;
    const float* src = x + (((size_t)(bt * 8 + bl) * NC + c) * 32 + s) * 32 + lg * 8;
    float4 v0 = ((const float4*)src)[0];
    float4 v1 = ((const float4*)src)[1];
    bf16x8 p;
    p[0] = (short)f2b(v0.x); p[1] = (short)f2b(v0.y);
    p[2] = (short)f2b(v0.z); p[3] = (short)f2b(v0.w);
    p[4] = (short)f2b(v1.x); p[5] = (short)f2b(v1.y);
    p[6] = (short)f2b(v1.z); p[7] = (short)f2b(v1.w);
    xf[sb] = p;
  }

  // ---- y accumulators (4 s-blocks x 2 d-blocks), bias-initialized ----
  f32x4 yacc[4][2];
  #pragma unroll
  for (int db = 0; db < 2; ++db) {
    f32x4 bv = *((const f32x4*)(b2 + db * 16 + lg * 4));
    #pragma unroll
    for (int mb = 0; mb < 4; ++mb) yacc[mb][db] = bv;
  }

  const f32x4 fzero = {0.f, 0.f, 0.f, 0.f};
  int row0 = 64 * w;

  for (int ch = 0; ch < 16; ++ch) {
    // GEMM1: hn(chunk of 32 h) = relu(x @ W1eff^T + b1eff), packed b64 stores
    #pragma unroll
    for (int hb = 0; hb < 2; ++hb) {
      int h0 = ch * 32 + hb * 16;
      bf16x8 wf = *(const bf16x8*)&W1c[(size_t)(h0 + lr) * 32 + lg * 8];
      f32x4 bias = *((const f32x4*)(b1e + h0 + lg * 4));
      #pragma unroll
      for (int sb = 0; sb < 4; ++sb) {
        f32x4 d = __builtin_amdgcn_mfma_f32_16x16x32_bf16(wf, xf[sb], fzero, 0, 0, 0);
        float r0 = fmaxf(d[0] + bias[0], 0.f);
        float r1 = fmaxf(d[1] + bias[1], 0.f);
        float r2 = fmaxf(d[2] + bias[2], 0.f);
        float r3 = fmaxf(d[3] + bias[3], 0.f);
        uint2 pk; pk.x = packbf2(r0, r1); pk.y = packbf2(r2, r3);
        *(uint2*)&buf[(row0 + sb * 16 + lr) * 40 + hb * 16 + lg * 4] = pk;
      }
    }
    // GEMM2: y += hn_chunk @ W2_chunk^T (swapped: A=W2 rows d, B=hn rows s)
    bf16x8 w20 = *(const bf16x8*)&W2B[(size_t)lr * 512 + ch * 32 + lg * 8];
    bf16x8 w21 = *(const bf16x8*)&W2B[(size_t)(16 + lr) * 512 + ch * 32 + lg * 8];
    #pragma unroll
    for (int mb = 0; mb < 4; ++mb) {
      bf16x8 hf = *(const bf16x8*)&buf[(row0 + mb * 16 + lr) * 40 + lg * 8];
      yacc[mb][0] = __builtin_amdgcn_mfma_f32_16x16x32_bf16(w20, hf, yacc[mb][0], 0, 0, 0);
      yacc[mb][1] = __builtin_amdgcn_mfma_f32_16x16x32_bf16(w21, hf, yacc[mb][1], 0, 0, 0);
    }
  }

  // ---- y -> bf16 into ybf region (aliases this wave's rbuf slice) ----
  #pragma unroll
  for (int mb = 0; mb < 4; ++mb) {
    int bl = 2 * w + (mb >> 1);
    int s = (mb & 1) * 16 + lr;
    #pragma unroll
    for (int db = 0; db < 2; ++db) {
      uint2 pk;
      pk.x = packbf2(yacc[mb][db][0], yacc[mb][db][1]);
      pk.y = packbf2(yacc[mb][db][2], yacc[mb][db][3]);
      *(uint2*)&buf[bl * 1280 + s * 40 + db * 16 + lg * 4] = pk;
    }
  }
  __syncthreads();

  // ---- fc via MFMA: M = 8 b (rows clamped), N = 32 o, K = 1024 ----
  int nt = w & 1, kh = w >> 1;
  int arow = (lr < 8) ? lr : 7;
  f32x4 zacc = {0.f, 0.f, 0.f, 0.f};
  #pragma unroll
  for (int ks = 0; ks < 16; ++ks) {
    int s = kh * 16 + ks;
    bf16x8 afc = *(const bf16x8*)&buf[arow * 1280 + s * 40 + lg * 8];
    bf16x8 bfc = *(const bf16x8*)&fcWB[(size_t)(nt * 16 + lr) * 1024 + s * 32 + lg * 8];
    zacc = __builtin_amdgcn_mfma_f32_16x16x32_bf16(afc, bfc, zacc, 0, 0, 0);
  }
  if (lg < 2) {
    #pragma unroll
    for (int r = 0; r < 4; ++r) zred[kh][lg * 4 + r][nt * 16 + lr] = zacc[r];
  }
  __syncthreads();
  {
    int bloc = t >> 5, o = t & 31;
    Z[((size_t)(bt * 8 + bloc) * NC + c) * 32 + o] =
        zred[0][bloc][o] + zred[1][bloc][o] + fcb[o];
  }
}

// ---------------- K4: normalize -> bf16 Zn, pos_sim, Z_out ----------------
__global__ void k_znorm(const float* __restrict__ Z, unsigned short* __restrict__ Znb,
                        float* __restrict__ possim, float* __restrict__ out) {
  int b = blockIdx.x;
  int t = threadIdx.x;        // 256: t = c*32 + d
  float v = Z[(size_t)b * 256 + t];
  float n2 = v * v;
  #pragma unroll
  for (int m = 16; m >= 1; m >>= 1) n2 += __shfl_xor(n2, m, 64);  // 32-lane seg = per-channel
  float nrm = fmaxf(sqrtf(n2), 1e-8f);
  float zn = v / nrm;
  Znb[(size_t)b * 256 + t] = f2b(zn);
  __shared__ float sz[256];
  __shared__ float szn[256];
  sz[t] = v; szn[t] = zn;
  __syncthreads();
  if (t < 32) {
    float s = 0.f;
    #pragma unroll
    for (int cc = 0; cc < 8; ++cc) s += sz[cc * 32 + t];
    out[(size_t)b * 32 + t] = s * 0.125f;
    float sd = 0.f, t1 = 0.f;
    #pragma unroll
    for (int cc = 0; cc < 8; ++cc) {
      float z2 = szn[cc * 32 + t];
      sd += z2; t1 = fmaf(z2, z2, t1);
    }
    float t2 = sd * sd;
    #pragma unroll
    for (int m = 16; m >= 1; m >>= 1) {
      t2 += __shfl_xor(t2, m, 64);
      t1 += __shfl_xor(t1, m, 64);
    }
    if (t == 0) possim[b] = (t2 - t1) * 0.5f / 28.0f;
  }
}

// ---------------- K5: negative-sim via gathered-A MFMA ----------------
__global__ __launch_bounds__(256) void k_negsim(
    const unsigned short* __restrict__ Znb, const int* __restrict__ neg_idx,
    const float* __restrict__ possim, float* __restrict__ lout) {
  int b = blockIdx.x;
  int t = threadIdx.x;   // 256 = 4 waves
  int w = t >> 6, l = t & 63;
  int lr = l & 15, lg = l >> 4;
  __shared__ uint4 selfv[32];          // self row, bf16 (512 B)
  __shared__ float rs[4];
  if (t < 32) selfv[t] = ((const uint4*)(Znb + (size_t)b * 256))[t];
  __syncthreads();
  const unsigned short* selfp = (const unsigned short*)selfv;
  const f32x4 fzero = {0.f, 0.f, 0.f, 0.f};
  float esum = 0.f;
  #pragma unroll 2
  for (int mb = 0; mb < 8; ++mb) {
    int m0 = w * 128 + mb * 16;
    int raw = neg_idx[(size_t)b * NNEG + m0 + lr];
    int j = raw + (raw >= b ? 1 : 0);
    const unsigned short* rp = Znb + (size_t)j * 256;
    f32x4 acc = fzero;
    #pragma unroll
    for (int ks = 0; ks < 8; ++ks) {
      bf16x8 af = *(const bf16x8*)(rp + ks * 32 + lg * 8);       // neg rows (M)
      bf16x8 bf = *(const bf16x8*)(selfp + ks * 32 + lg * 8);    // self broadcast (N)
      acc = __builtin_amdgcn_mfma_f32_16x16x32_bf16(af, bf, acc, 0, 0, 0);
    }
    if (lr == 0) {
      esum += expf(acc[0] * 0.25f) + expf(acc[1] * 0.25f)
            + expf(acc[2] * 0.25f) + expf(acc[3] * 0.25f);
    }
  }
  #pragma unroll
  for (int m = 32; m >= 1; m >>= 1) esum += __shfl_xor(esum, m, 64);
  if (l == 0) rs[w] = esum;
  __syncthreads();
  if (t == 0) {
    float tot = rs[0] + rs[1] + rs[2] + rs[3];
    lout[b] = expf(possim[b] * 2.0f) / tot;
  }
}

extern "C" void kernel_launch(void* const* d_in, const int* in_sizes, int n_in,
                              void* d_out, int out_size, void* d_ws, size_t ws_size,
                              hipStream_t stream) {
  const float* x     = (const float*)d_in[0];
  const float* W1    = (const float*)d_in[1];
  const float* b1    = (const float*)d_in[2];
  const float* gamma = (const float*)d_in[3];
  const float* beta  = (const float*)d_in[4];
  const float* W2    = (const float*)d_in[5];
  const float* b2    = (const float*)d_in[6];
  const float* fcW   = (const float*)d_in[7];
  const float* fcb   = (const float*)d_in[8];
  const int*   nidx  = (const int*)d_in[9];
  float* ws = (float*)d_ws;
  float* Ssum   = ws + WS_SSUM;
  float* Sprod  = ws + WS_SPROD;
  float* b1eff  = ws + WS_B1EFF;
  float* Z      = ws + WS_Z;
  float* possim = ws + WS_POS;
  unsigned short* W1Bp  = (unsigned short*)(ws + WS_W1B);
  unsigned short* W2Bp  = (unsigned short*)(ws + WS_W2B);
  unsigned short* fcWBp = (unsigned short*)(ws + WS_FCWB);
  unsigned short* Znbp  = (unsigned short*)(ws + WS_ZNB);
  float* out = (float*)d_out;

  hipMemsetAsync(ws, 0, (256 + 8192) * sizeof(float), stream);
  k_stats<<<dim3(256, 8), 256, 0, stream>>>(x, Ssum, Sprod);
  k_foldcvt<<<144, 256, 0, stream>>>(W1, b1, gamma, beta, Ssum, Sprod, W2, fcW,
                                     W1Bp, b1eff, W2Bp, fcWBp);
  k_main<<<dim3(256, 8), 256, 0, stream>>>(x, W1Bp, b1eff, W2Bp, b2, fcWBp, fcb, Z);
  k_znorm<<<NB, 256, 0, stream>>>(Z, Znbp, possim, out);
  k_negsim<<<NB, 256, 0, stream>>>(Znbp, nidx, possim, out + NB * 32);
}

// Round 4
// 178.632 us; speedup vs baseline: 7.9651x; 1.4387x over previous
//
#include <hip/hip_runtime.h>
#include <hip/hip_bf16.h>
#include <math.h>

#define NB 2048
#define NC 8
#define NNEG 512

typedef __attribute__((ext_vector_type(8))) short bf16x8;
typedef __attribute__((ext_vector_type(4))) float f32x4;
typedef __attribute__((ext_vector_type(16))) float f32x16;

static __device__ __forceinline__ unsigned short f2b(float f) {
  __hip_bfloat16 h = __float2bfloat16(f);
  return *reinterpret_cast<unsigned short*>(&h);
}
static __device__ __forceinline__ unsigned int packbf2(float a, float b) {
  return (unsigned int)f2b(a) | ((unsigned int)f2b(b) << 16);
}

// ---- ws layout (float offsets) ----
#define WS_SSUM   0          // [8][32]
#define WS_SPROD  256        // [8][32][32]
#define WS_B1EFF  8448       // [8][512] f32
#define WS_Z      12544      // [2048][8][32] f32
#define WS_POS    536832     // [2048] f32
#define WS_W1B    538880     // ushort [8][512][32]
#define WS_W2B    604416     // ushort [32][512]
#define WS_FCWB   612608     // ushort [32][1024]
#define WS_ZNB    628992     // ushort [2048][256] (bf16 Zn)
// end: 891136 floats = 3.56 MB

// ---------------- K1: moments via MFMA (Sprod = X^T X on matrix pipe) ----------------
// Fragment trick: lane l holds column (l&31) of rows (l>>5)*8+j of a 16-row chunk.
// A-layout and B-layout of mfma_32x32x16 are mirrors -> mfma(f, f, acc) = X^T X.
__global__ __launch_bounds__(256) void k_stats(const float* __restrict__ x,
                        float* __restrict__ Ssum, float* __restrict__ Sprod) {
  int c = blockIdx.y;
  int t = threadIdx.x;
  int w = t >> 6, l = t & 63;
  int col = l & 31, half = l >> 5;
  f32x16 acc;
  #pragma unroll
  for (int r = 0; r < 16; ++r) acc[r] = 0.f;
  float ssum = 0.f;
  #pragma unroll 2
  for (int i = 0; i < 8; ++i) {
    int chunk = blockIdx.x * 32 + i * 4 + w;          // 16-row chunk of channel c
    int b = chunk >> 1;
    int sb = (chunk & 1) * 16 + half * 8;
    const float* base = x + ((size_t)(b * NC + c)) * 1024 + sb * 32 + col;
    float v0 = base[0],   v1 = base[32],  v2 = base[64],  v3 = base[96];
    float v4 = base[128], v5 = base[160], v6 = base[192], v7 = base[224];
    ssum += ((v0 + v1) + (v2 + v3)) + ((v4 + v5) + (v6 + v7));
    bf16x8 f;
    f[0] = (short)f2b(v0); f[1] = (short)f2b(v1);
    f[2] = (short)f2b(v2); f[3] = (short)f2b(v3);
    f[4] = (short)f2b(v4); f[5] = (short)f2b(v5);
    f[6] = (short)f2b(v6); f[7] = (short)f2b(v7);
    acc = __builtin_amdgcn_mfma_f32_32x32x16_bf16(f, f, acc, 0, 0, 0);
  }
  // ---- block reduction (once per block, not per tile) ----
  __shared__ float pr[4][1024];
  __shared__ float sred[4][32];
  #pragma unroll
  for (int r = 0; r < 16; ++r) {
    int row = (r & 3) + 8 * (r >> 2) + 4 * half;
    pr[w][row * 32 + col] = acc[r];
  }
  float sv = ssum + __shfl_xor(ssum, 32);
  if (l < 32) sred[w][l] = sv;
  __syncthreads();
  #pragma unroll
  for (int p = 0; p < 4; ++p) {
    int cell = t + p * 256;
    atomicAdd(&Sprod[c * 1024 + cell],
              (pr[0][cell] + pr[1][cell]) + (pr[2][cell] + pr[3][cell]));
  }
  if (t < 32)
    atomicAdd(&Ssum[c * 32 + t],
              (sred[0][t] + sred[1][t]) + (sred[2][t] + sred[3][t]));
}

// ---------------- K2: fold BN into W1 (bf16) + convert W2/fcW ----------------
__global__ void k_foldcvt(const float* __restrict__ W1, const float* __restrict__ b1,
                       const float* __restrict__ gamma, const float* __restrict__ beta,
                       const float* __restrict__ Ssum, const float* __restrict__ Sprod,
                       const float* __restrict__ W2, const float* __restrict__ fcW,
                       unsigned short* __restrict__ W1B, float* __restrict__ b1eff,
                       unsigned short* __restrict__ W2B, unsigned short* __restrict__ fcWB) {
  if (blockIdx.x >= 16) {
    int i = (blockIdx.x - 16) * 256 + threadIdx.x;   // 0..32767
    if (i < 32 * 512) W2B[i] = f2b(W2[i]);
    fcWB[i] = f2b(fcW[i]);
    return;
  }
  int g = blockIdx.x * 256 + threadIdx.x;   // 0..4095
  int c = g >> 9, h = g & 511;
  const float invN = 1.0f / (float)(NB * 32);
  float w[32];
  #pragma unroll
  for (int d = 0; d < 32; ++d) w[d] = W1[h * 32 + d];
  const float* M = Sprod + c * 1024;
  float q = 0.f;
  for (int j = 0; j < 32; ++j) {
    float v = 0.f;
    #pragma unroll
    for (int i2 = 0; i2 < 32; ++i2) v = fmaf(w[i2], M[i2 * 32 + j], v);
    q = fmaf(v, w[j], q);
  }
  float wmu = 0.f;
  #pragma unroll
  for (int d = 0; d < 32; ++d) wmu = fmaf(w[d], Ssum[c * 32 + d] * invN, wmu);
  float bb = b1[h];
  float mean = wmu + bb;
  float e2 = q * invN + 2.f * bb * wmu + bb * bb;
  float var = e2 - mean * mean;
  float alpha = gamma[h] * rsqrtf(var + 1e-5f);
  #pragma unroll
  for (int d = 0; d < 32; ++d)
    W1B[((size_t)c * 512 + h) * 32 + d] = f2b(w[d] * alpha);
  b1eff[c * 512 + h] = (bb - mean) * alpha + beta[h];
}

// ---------------- K3: fused MFMA  x->h->relu->y->Z  (8 b / block) ----------------
__global__ __launch_bounds__(256, 4) void k_main(
    const float* __restrict__ x, const unsigned short* __restrict__ W1B,
    const float* __restrict__ b1eff, const unsigned short* __restrict__ W2B,
    const float* __restrict__ b2, const unsigned short* __restrict__ fcWB,
    const float* __restrict__ fcb, float* __restrict__ Z) {
  int c = blockIdx.y;
  int bt = blockIdx.x;            // 256 tiles of 8 b each
  int t = threadIdx.x;
  int w = t >> 6, l = t & 63;
  int lr = l & 15, lg = l >> 4;

  // wave-private union: rbuf rows [64w,64w+64) x 40  ==  ybf b {2w,2w+1} x 1280
  __shared__ unsigned short buf[8 * 1280];   // 20480 B
  __shared__ float zred[2][8][32];

  const unsigned short* W1c = W1B + (size_t)c * 512 * 32;
  const float* b1e = b1eff + c * 512;

  // ---- x B-fragments direct from global (4 sub-blocks of 16 rows each) ----
  bf16x8 xf[4];
  #pragma unroll
  for (int sb = 0; sb < 4; ++sb) {
    int bl = 2 * w + (sb >> 1);
    int s = (sb & 1) * 16 + lr;
    const float* src = x + (((size_t)(bt * 8 + bl) * NC + c) * 32 + s) * 32 + lg * 8;
    float4 v0 = ((const float4*)src)[0];
    float4 v1 = ((const float4*)src)[1];
    bf16x8 p;
    p[0] = (short)f2b(v0.x); p[1] = (short)f2b(v0.y);
    p[2] = (short)f2b(v0.z); p[3] = (short)f2b(v0.w);
    p[4] = (short)f2b(v1.x); p[5] = (short)f2b(v1.y);
    p[6] = (short)f2b(v1.z); p[7] = (short)f2b(v1.w);
    xf[sb] = p;
  }

  // ---- y accumulators (4 s-blocks x 2 d-blocks), bias-initialized ----
  f32x4 yacc[4][2];
  #pragma unroll
  for (int db = 0; db < 2; ++db) {
    f32x4 bv = *((const f32x4*)(b2 + db * 16 + lg * 4));
    #pragma unroll
    for (int mb = 0; mb < 4; ++mb) yacc[mb][db] = bv;
  }

  const f32x4 fzero = {0.f, 0.f, 0.f, 0.f};
  int row0 = 64 * w;

  for (int ch = 0; ch < 16; ++ch) {
    // GEMM1: hn(chunk of 32 h) = relu(x @ W1eff^T + b1eff), packed b64 stores
    #pragma unroll
    for (int hb = 0; hb < 2; ++hb) {
      int h0 = ch * 32 + hb * 16;
      bf16x8 wf = *(const bf16x8*)&W1c[(size_t)(h0 + lr) * 32 + lg * 8];
      f32x4 bias = *((const f32x4*)(b1e + h0 + lg * 4));
      #pragma unroll
      for (int sb = 0; sb < 4; ++sb) {
        f32x4 d = __builtin_amdgcn_mfma_f32_16x16x32_bf16(wf, xf[sb], fzero, 0, 0, 0);
        float r0 = fmaxf(d[0] + bias[0], 0.f);
        float r1 = fmaxf(d[1] + bias[1], 0.f);
        float r2 = fmaxf(d[2] + bias[2], 0.f);
        float r3 = fmaxf(d[3] + bias[3], 0.f);
        uint2 pk; pk.x = packbf2(r0, r1); pk.y = packbf2(r2, r3);
        *(uint2*)&buf[(row0 + sb * 16 + lr) * 40 + hb * 16 + lg * 4] = pk;
      }
    }
    // GEMM2: y += hn_chunk @ W2_chunk^T (swapped: A=W2 rows d, B=hn rows s)
    bf16x8 w20 = *(const bf16x8*)&W2B[(size_t)lr * 512 + ch * 32 + lg * 8];
    bf16x8 w21 = *(const bf16x8*)&W2B[(size_t)(16 + lr) * 512 + ch * 32 + lg * 8];
    #pragma unroll
    for (int mb = 0; mb < 4; ++mb) {
      bf16x8 hf = *(const bf16x8*)&buf[(row0 + mb * 16 + lr) * 40 + lg * 8];
      yacc[mb][0] = __builtin_amdgcn_mfma_f32_16x16x32_bf16(w20, hf, yacc[mb][0], 0, 0, 0);
      yacc[mb][1] = __builtin_amdgcn_mfma_f32_16x16x32_bf16(w21, hf, yacc[mb][1], 0, 0, 0);
    }
  }

  // ---- y -> bf16 into ybf region (aliases this wave's rbuf slice) ----
  #pragma unroll
  for (int mb = 0; mb < 4; ++mb) {
    int bl = 2 * w + (mb >> 1);
    int s = (mb & 1) * 16 + lr;
    #pragma unroll
    for (int db = 0; db < 2; ++db) {
      uint2 pk;
      pk.x = packbf2(yacc[mb][db][0], yacc[mb][db][1]);
      pk.y = packbf2(yacc[mb][db][2], yacc[mb][db][3]);
      *(uint2*)&buf[bl * 1280 + s * 40 + db * 16 + lg * 4] = pk;
    }
  }
  __syncthreads();

  // ---- fc via MFMA: M = 8 b (rows clamped), N = 32 o, K = 1024 ----
  int nt = w & 1, kh = w >> 1;
  int arow = (lr < 8) ? lr : 7;
  f32x4 zacc = {0.f, 0.f, 0.f, 0.f};
  #pragma unroll
  for (int ks = 0; ks < 16; ++ks) {
    int s = kh * 16 + ks;
    bf16x8 afc = *(const bf16x8*)&buf[arow * 1280 + s * 40 + lg * 8];
    bf16x8 bfc = *(const bf16x8*)&fcWB[(size_t)(nt * 16 + lr) * 1024 + s * 32 + lg * 8];
    zacc = __builtin_amdgcn_mfma_f32_16x16x32_bf16(afc, bfc, zacc, 0, 0, 0);
  }
  if (lg < 2) {
    #pragma unroll
    for (int r = 0; r < 4; ++r) zred[kh][lg * 4 + r][nt * 16 + lr] = zacc[r];
  }
  __syncthreads();
  {
    int bloc = t >> 5, o = t & 31;
    Z[((size_t)(bt * 8 + bloc) * NC + c) * 32 + o] =
        zred[0][bloc][o] + zred[1][bloc][o] + fcb[o];
  }
}

// ---------------- K4: normalize -> bf16 Zn, pos_sim, Z_out ----------------
__global__ void k_znorm(const float* __restrict__ Z, unsigned short* __restrict__ Znb,
                        float* __restrict__ possim, float* __restrict__ out) {
  int b = blockIdx.x;
  int t = threadIdx.x;        // 256: t = c*32 + d
  float v = Z[(size_t)b * 256 + t];
  float n2 = v * v;
  #pragma unroll
  for (int m = 16; m >= 1; m >>= 1) n2 += __shfl_xor(n2, m, 64);  // 32-lane seg = per-channel
  float nrm = fmaxf(sqrtf(n2), 1e-8f);
  float zn = v / nrm;
  Znb[(size_t)b * 256 + t] = f2b(zn);
  __shared__ float sz[256];
  __shared__ float szn[256];
  sz[t] = v; szn[t] = zn;
  __syncthreads();
  if (t < 32) {
    float s = 0.f;
    #pragma unroll
    for (int cc = 0; cc < 8; ++cc) s += sz[cc * 32 + t];
    out[(size_t)b * 32 + t] = s * 0.125f;
    float sd = 0.f, t1 = 0.f;
    #pragma unroll
    for (int cc = 0; cc < 8; ++cc) {
      float z2 = szn[cc * 32 + t];
      sd += z2; t1 = fmaf(z2, z2, t1);
    }
    float t2 = sd * sd;
    #pragma unroll
    for (int m = 16; m >= 1; m >>= 1) {
      t2 += __shfl_xor(t2, m, 64);
      t1 += __shfl_xor(t1, m, 64);
    }
    if (t == 0) possim[b] = (t2 - t1) * 0.5f / 28.0f;
  }
}

// ---------------- K5: negative-sim via gathered-A MFMA ----------------
__global__ __launch_bounds__(256) void k_negsim(
    const unsigned short* __restrict__ Znb, const int* __restrict__ neg_idx,
    const float* __restrict__ possim, float* __restrict__ lout) {
  int b = blockIdx.x;
  int t = threadIdx.x;   // 256 = 4 waves
  int w = t >> 6, l = t & 63;
  int lr = l & 15, lg = l >> 4;
  __shared__ uint4 selfv[32];          // self row, bf16 (512 B)
  __shared__ float rs[4];
  if (t < 32) selfv[t] = ((const uint4*)(Znb + (size_t)b * 256))[t];
  __syncthreads();
  const unsigned short* selfp = (const unsigned short*)selfv;
  const f32x4 fzero = {0.f, 0.f, 0.f, 0.f};
  float esum = 0.f;
  #pragma unroll 2
  for (int mb = 0; mb < 8; ++mb) {
    int m0 = w * 128 + mb * 16;
    int raw = neg_idx[(size_t)b * NNEG + m0 + lr];
    int j = raw + (raw >= b ? 1 : 0);
    const unsigned short* rp = Znb + (size_t)j * 256;
    f32x4 acc = fzero;
    #pragma unroll
    for (int ks = 0; ks < 8; ++ks) {
      bf16x8 af = *(const bf16x8*)(rp + ks * 32 + lg * 8);       // neg rows (M)
      bf16x8 bf = *(const bf16x8*)(selfp + ks * 32 + lg * 8);    // self broadcast (N)
      acc = __builtin_amdgcn_mfma_f32_16x16x32_bf16(af, bf, acc, 0, 0, 0);
    }
    if (lr == 0) {
      esum += expf(acc[0] * 0.25f) + expf(acc[1] * 0.25f)
            + expf(acc[2] * 0.25f) + expf(acc[3] * 0.25f);
    }
  }
  #pragma unroll
  for (int m = 32; m >= 1; m >>= 1) esum += __shfl_xor(esum, m, 64);
  if (l == 0) rs[w] = esum;
  __syncthreads();
  if (t == 0) {
    float tot = rs[0] + rs[1] + rs[2] + rs[3];
    lout[b] = expf(possim[b] * 2.0f) / tot;
  }
}

extern "C" void kernel_launch(void* const* d_in, const int* in_sizes, int n_in,
                              void* d_out, int out_size, void* d_ws, size_t ws_size,
                              hipStream_t stream) {
  const float* x     = (const float*)d_in[0];
  const float* W1    = (const float*)d_in[1];
  const float* b1    = (const float*)d_in[2];
  const float* gamma = (const float*)d_in[3];
  const float* beta  = (const float*)d_in[4];
  const float* W2    = (const float*)d_in[5];
  const float* b2    = (const float*)d_in[6];
  const float* fcW   = (const float*)d_in[7];
  const float* fcb   = (const float*)d_in[8];
  const int*   nidx  = (const int*)d_in[9];
  float* ws = (float*)d_ws;
  float* Ssum   = ws + WS_SSUM;
  float* Sprod  = ws + WS_SPROD;
  float* b1eff  = ws + WS_B1EFF;
  float* Z      = ws + WS_Z;
  float* possim = ws + WS_POS;
  unsigned short* W1Bp  = (unsigned short*)(ws + WS_W1B);
  unsigned short* W2Bp  = (unsigned short*)(ws + WS_W2B);
  unsigned short* fcWBp = (unsigned short*)(ws + WS_FCWB);
  unsigned short* Znbp  = (unsigned short*)(ws + WS_ZNB);
  float* out = (float*)d_out;

  hipMemsetAsync(ws, 0, (256 + 8192) * sizeof(float), stream);
  k_stats<<<dim3(128, 8), 256, 0, stream>>>(x, Ssum, Sprod);
  k_foldcvt<<<144, 256, 0, stream>>>(W1, b1, gamma, beta, Ssum, Sprod, W2, fcW,
                                     W1Bp, b1eff, W2Bp, fcWBp);
  k_main<<<dim3(256, 8), 256, 0, stream>>>(x, W1Bp, b1eff, W2Bp, b2, fcWBp, fcb, Z);
  k_znorm<<<NB, 256, 0, stream>>>(Z, Znbp, possim, out);
  k_negsim<<<NB, 256, 0, stream>>>(Znbp, nidx, possim, out + NB * 32);
}